// Round 1
// baseline (137.360 us; speedup 1.0000x reference)
//
#include <hip/hip_runtime.h>
#include <math.h>

#define SEQ 250
#define NCLS 12

// One block per batch element. 256 threads.
// LDS: 5 x (250*16 f32) + 256 f32 = 81,024 B  -> 2 blocks/CU.
__global__ __launch_bounds__(256, 2)
void mamba_cls_kernel(
    const float* __restrict__ x,         // (B, 8, 250)
    const float* __restrict__ in_proj_w, // (32, 8)
    const float* __restrict__ conv_w,    // (16, 4)
    const float* __restrict__ conv_b,    // (16)
    const float* __restrict__ x_proj_w,  // (33, 16)
    const float* __restrict__ dt_proj_w, // (16, 1)
    const float* __restrict__ dt_proj_b, // (16)
    const float* __restrict__ A_log,     // (16, 16)
    const float* __restrict__ Dp,        // (16)
    const float* __restrict__ out_proj_w,// (8, 16)
    const float* __restrict__ fc_w,      // (12, 2000)
    const float* __restrict__ fc_b,      // (12)
    float* __restrict__ out)             // (B, 12)
{
    __shared__ float s_xin[SEQ * 16];  // x_in (ph1-2); y (ph4-5)
    __shared__ float s_u  [SEQ * 16];  // u (ph2-5)
    __shared__ float s_B  [SEQ * 16];
    __shared__ float s_C  [SEQ * 16];
    __shared__ float s_dl [SEQ * 16];  // delta (ph3b-4); out-proj 2000 (ph5b-6)
    __shared__ float s_dt [256];       // dt 250 (ph3); reduce buf (ph6)

    const int b = blockIdx.x;
    const int tid = threadIdx.x;
    const float* __restrict__ xb = x + (size_t)b * (8 * SEQ);

    // ---- Phase 1: x_in[t,d] = sum_m x[b,m,t] * in_proj_w[d,m]
    {
        const int d = tid & 15;
        float w[8];
        #pragma unroll
        for (int m = 0; m < 8; ++m) w[m] = in_proj_w[d * 8 + m];
        for (int t = tid >> 4; t < SEQ; t += 16) {
            float acc = 0.f;
            #pragma unroll
            for (int m = 0; m < 8; ++m) acc += w[m] * xb[m * SEQ + t];
            s_xin[t * 16 + d] = acc;
        }
    }
    __syncthreads();

    // ---- Phase 2: causal depthwise conv (k=4) + SiLU -> u
    {
        const int d = tid & 15;
        float cw[4];
        #pragma unroll
        for (int k = 0; k < 4; ++k) cw[k] = conv_w[d * 4 + k];
        const float cb = conv_b[d];
        for (int t = tid >> 4; t < SEQ; t += 16) {
            float acc = cb;
            #pragma unroll
            for (int k = 0; k < 4; ++k) {
                int tt = t + k - 3;
                if (tt >= 0) acc += cw[k] * s_xin[tt * 16 + d];
            }
            float sg = 1.f / (1.f + __expf(-acc));
            s_u[t * 16 + d] = acc * sg;
        }
    }
    __syncthreads();

    // ---- Phase 3a: x_dbl = u @ x_proj_w.T -> dt(250), B(250x16), C(250x16)
    {
        const int s = tid & 15;
        float wb[16], wc[16];
        #pragma unroll
        for (int d2 = 0; d2 < 16; ++d2) wb[d2] = x_proj_w[(1 + s) * 16 + d2];
        #pragma unroll
        for (int d2 = 0; d2 < 16; ++d2) wc[d2] = x_proj_w[(17 + s) * 16 + d2];
        for (int t = tid >> 4; t < SEQ; t += 16) {
            float ab = 0.f, ac = 0.f;
            #pragma unroll
            for (int d2 = 0; d2 < 16; ++d2) {
                float uv = s_u[t * 16 + d2];
                ab += wb[d2] * uv;
                ac += wc[d2] * uv;
            }
            s_B[t * 16 + s] = ab;
            s_C[t * 16 + s] = ac;
        }
        if (tid < SEQ) {
            float a = 0.f;
            #pragma unroll
            for (int d2 = 0; d2 < 16; ++d2) a += x_proj_w[d2] * s_u[tid * 16 + d2];
            s_dt[tid] = a;
        }
    }
    __syncthreads();

    // ---- Phase 3b: delta[t,d] = softplus(dt[t]*dt_proj_w[d] + dt_proj_b[d])
    {
        const int d = tid & 15;
        const float dw = dt_proj_w[d];
        const float db = dt_proj_b[d];
        for (int t = tid >> 4; t < SEQ; t += 16) {
            float v = s_dt[t] * dw + db;
            float sp = (v > 20.f) ? v : __logf(1.f + __expf(v));
            s_dl[t * 16 + d] = sp;
        }
    }
    __syncthreads();

    // ---- Phase 4: sequential scan. thread = (d = tid>>4, s = tid&15)
    {
        const int d = tid >> 4;
        const int s = tid & 15;
        const float A = -__expf(A_log[d * 16 + s]);
        float h = 0.f;
        for (int t = 0; t < SEQ; ++t) {
            float dl = s_dl[t * 16 + d];   // broadcast across s
            float uv = s_u [t * 16 + d];   // broadcast across s
            float Bv = s_B [t * 16 + s];   // broadcast across d
            float Cv = s_C [t * 16 + s];
            float dA = __expf(dl * A);
            h = dA * h + dl * Bv * uv;
            float r = h * Cv;
            r += __shfl_xor(r, 1);
            r += __shfl_xor(r, 2);
            r += __shfl_xor(r, 4);
            r += __shfl_xor(r, 8);
            if (s == 0) s_xin[t * 16 + d] = r;  // y[t,d]
        }
    }
    __syncthreads();

    // ---- Phase 5: y = (y + u*D) * silu(z), z recomputed from x
    {
        const int d = tid & 15;
        float w[8];
        #pragma unroll
        for (int m = 0; m < 8; ++m) w[m] = in_proj_w[(16 + d) * 8 + m];
        const float Dd = Dp[d];
        for (int t = tid >> 4; t < SEQ; t += 16) {
            float z = 0.f;
            #pragma unroll
            for (int m = 0; m < 8; ++m) z += w[m] * xb[m * SEQ + t];
            float sz = z / (1.f + __expf(-z));
            float yv = s_xin[t * 16 + d] + s_u[t * 16 + d] * Dd;
            s_xin[t * 16 + d] = yv * sz;
        }
    }
    __syncthreads();

    // ---- Phase 5b: out[t,j] = sum_d y[t,d] * out_proj_w[j,d]  (into s_dl, 2000)
    {
        const int j = tid & 7;
        float w[16];
        #pragma unroll
        for (int d2 = 0; d2 < 16; ++d2) w[d2] = out_proj_w[j * 16 + d2];
        for (int t = tid >> 3; t < SEQ; t += 32) {
            float a = 0.f;
            #pragma unroll
            for (int d2 = 0; d2 < 16; ++d2) a += w[d2] * s_xin[t * 16 + d2];
            s_dl[t * 8 + j] = a;
        }
    }
    __syncthreads();

    // ---- Phase 6: logits[c] = flat(2000) . fc_w[c,:] + fc_b[c]
    {
        float p[NCLS];
        #pragma unroll
        for (int c = 0; c < NCLS; ++c) p[c] = 0.f;
        for (int idx = tid; idx < 2000; idx += 256) {
            float f = s_dl[idx];
            #pragma unroll
            for (int c = 0; c < NCLS; ++c) p[c] += f * fc_w[c * 2000 + idx];
        }
        #pragma unroll
        for (int c = 0; c < NCLS; ++c) {
            float v = p[c];
            v += __shfl_xor(v, 1);
            v += __shfl_xor(v, 2);
            v += __shfl_xor(v, 4);
            v += __shfl_xor(v, 8);
            v += __shfl_xor(v, 16);
            v += __shfl_xor(v, 32);
            p[c] = v;
        }
        const int wave = tid >> 6;
        const int lane = tid & 63;
        if (lane == 0) {
            #pragma unroll
            for (int c = 0; c < NCLS; ++c) s_dt[wave * NCLS + c] = p[c];
        }
        __syncthreads();
        if (tid < NCLS) {
            float v = s_dt[tid] + s_dt[NCLS + tid] + s_dt[2 * NCLS + tid] +
                      s_dt[3 * NCLS + tid] + fc_b[tid];
            out[(size_t)b * NCLS + tid] = v;
        }
    }
}

extern "C" void kernel_launch(void* const* d_in, const int* in_sizes, int n_in,
                              void* d_out, int out_size, void* d_ws, size_t ws_size,
                              hipStream_t stream) {
    const float* x          = (const float*)d_in[0];
    const float* in_proj_w  = (const float*)d_in[1];
    const float* conv_w     = (const float*)d_in[2];
    const float* conv_b     = (const float*)d_in[3];
    const float* x_proj_w   = (const float*)d_in[4];
    const float* dt_proj_w  = (const float*)d_in[5];
    const float* dt_proj_b  = (const float*)d_in[6];
    const float* A_log      = (const float*)d_in[7];
    const float* Dp         = (const float*)d_in[8];
    const float* out_proj_w = (const float*)d_in[9];
    const float* fc_w       = (const float*)d_in[10];
    const float* fc_b       = (const float*)d_in[11];
    float* out = (float*)d_out;

    const int batch = in_sizes[0] / (8 * SEQ);  // 1024
    mamba_cls_kernel<<<batch, 256, 0, stream>>>(
        x, in_proj_w, conv_w, conv_b, x_proj_w, dt_proj_w, dt_proj_b,
        A_log, Dp, out_proj_w, fc_w, fc_b, out);
}

// Round 2
// 103.788 us; speedup vs baseline: 1.3235x; 1.3235x over previous
//
#include <hip/hip_runtime.h>
#include <math.h>

#define SEQ 250
#define NCLS 12

// Butterfly add via DPP (within 16-lane rows, zero DS-pipe ops).
// xor1: quad_perm(1,0,3,2)=0xB1; xor2: quad_perm(2,3,0,1)=0x4E;
// xor4-equiv: row_half_mirror=0x141 (lane^7 — values already constant per quad);
// xor8-equiv: row_mirror=0x140 (lane^15).
template<int CTRL>
__device__ __forceinline__ float dpp_add(float v) {
    int t = __builtin_amdgcn_update_dpp(0, __float_as_int(v), CTRL, 0xF, 0xF, true);
    return v + __int_as_float(t);
}

// One block per batch element. 256 threads.
// LDS: s_bc2 32000 + s_dlu2 32000 + s_x 8000 + s_dt 1024 = 73,024 B -> 2 blocks/CU.
__global__ __launch_bounds__(256, 2)
void mamba_cls_kernel(
    const float* __restrict__ x,         // (B, 8, 250)
    const float* __restrict__ in_proj_w, // (32, 8)
    const float* __restrict__ conv_w,    // (16, 4)
    const float* __restrict__ conv_b,    // (16)
    const float* __restrict__ x_proj_w,  // (33, 16)
    const float* __restrict__ dt_proj_w, // (16, 1)
    const float* __restrict__ dt_proj_b, // (16)
    const float* __restrict__ A_log,     // (16, 16)
    const float* __restrict__ Dp,        // (16)
    const float* __restrict__ out_proj_w,// (8, 16)
    const float* __restrict__ fc_w,      // (12, 2000)
    const float* __restrict__ fc_b,      // (12)
    float* __restrict__ out)             // (B, 12)
{
    __shared__ float2 s_bc2 [SEQ * 16];  // ph1-2: x_in (float view); ph3a+: {B,C}; ph5b: out2000 (float view)
    __shared__ float2 s_dlu2[SEQ * 16];  // {dl -> y -> y_gated, u} pairs
    __shared__ float  s_x   [8 * SEQ];   // staged input row (2000 floats)
    __shared__ float  s_dt  [256];       // dt(250); ph6 reduce buffer

    const int b   = blockIdx.x;
    const int tid = threadIdx.x;
    float* s_f   = (float*)s_bc2;
    float* s_dlu = (float*)s_dlu2;

    // ---- Phase 0: stage x coalesced into LDS
    {
        const float* __restrict__ xb = x + (size_t)b * (8 * SEQ);
        for (int i = tid; i < 8 * SEQ; i += 256) s_x[i] = xb[i];
    }
    __syncthreads();

    // ---- Phase 1: x_in[t,d] = sum_m x[m,t] * in_proj_w[d,m]   (into s_f)
    {
        const int d = tid & 15;
        float w[8];
        #pragma unroll
        for (int m = 0; m < 8; ++m) w[m] = in_proj_w[d * 8 + m];
        for (int t = tid >> 4; t < SEQ; t += 16) {
            float acc = 0.f;
            #pragma unroll
            for (int m = 0; m < 8; ++m) acc += w[m] * s_x[m * SEQ + t];
            s_f[t * 16 + d] = acc;
        }
    }
    __syncthreads();

    // ---- Phase 2: causal depthwise conv (k=4) + SiLU -> u (odd slots of s_dlu)
    {
        const int d = tid & 15;
        float cw[4];
        #pragma unroll
        for (int k = 0; k < 4; ++k) cw[k] = conv_w[d * 4 + k];
        const float cb = conv_b[d];
        for (int t = tid >> 4; t < SEQ; t += 16) {
            float acc = cb;
            #pragma unroll
            for (int k = 0; k < 4; ++k) {
                int tt = t + k - 3;
                if (tt >= 0) acc += cw[k] * s_f[tt * 16 + d];
            }
            float sg = 1.f / (1.f + __expf(-acc));
            s_dlu[t * 32 + d * 2 + 1] = acc * sg;
        }
    }
    __syncthreads();

    // ---- Phase 3a: {B,C} pairs (overwrites x_in region) + dt(250)
    {
        const int s = tid & 15;
        float wb[16], wc[16];
        #pragma unroll
        for (int d2 = 0; d2 < 16; ++d2) wb[d2] = x_proj_w[(1 + s) * 16 + d2];
        #pragma unroll
        for (int d2 = 0; d2 < 16; ++d2) wc[d2] = x_proj_w[(17 + s) * 16 + d2];
        for (int t = tid >> 4; t < SEQ; t += 16) {
            float ab = 0.f, ac = 0.f;
            #pragma unroll
            for (int d2 = 0; d2 < 16; ++d2) {
                float uv = s_dlu[t * 32 + d2 * 2 + 1];
                ab += wb[d2] * uv;
                ac += wc[d2] * uv;
            }
            s_bc2[t * 16 + s] = make_float2(ab, ac);
        }
        if (tid < SEQ) {
            float a = 0.f;
            #pragma unroll
            for (int d2 = 0; d2 < 16; ++d2)
                a += x_proj_w[d2] * s_dlu[tid * 32 + d2 * 2 + 1];
            s_dt[tid] = a;
        }
    }
    __syncthreads();

    // ---- Phase 3b: dl[t,d] = softplus(dt[t]*dt_proj_w[d] + dt_proj_b[d]) (even slots)
    {
        const int d = tid & 15;
        const float dw = dt_proj_w[d];
        const float db = dt_proj_b[d];
        for (int t = tid >> 4; t < SEQ; t += 16) {
            float v = s_dt[t] * dw + db;
            float sp = (v > 20.f) ? v : __logf(1.f + __expf(v));
            s_dlu[t * 32 + d * 2] = sp;
        }
    }
    __syncthreads();

    // ---- Phase 4: scan. thread = (d = tid>>4, s = tid&15).
    // h = exp(dl*A)*h + dl*B*u ; y[t,d] = sum_s h*C + u*D  (y overwrites dl slot)
    {
        const int d = tid >> 4;
        const int s = tid & 15;
        const float A2 = -__expf(A_log[d * 16 + s]) * 1.4426950408889634f;
        const float Dd = Dp[d];
        const float2* __restrict__ dl_p = s_dlu2 + d;
        const float2* __restrict__ bc_p = s_bc2 + s;
        float h = 0.f;
        #pragma unroll 5
        for (int t = 0; t < SEQ; ++t) {
            float2 dlu = dl_p[t * 16];      // {dl, u} broadcast across s
            float2 bc  = bc_p[t * 16];      // {B, C} broadcast across d
            float dA = exp2f(dlu.x * A2);
            h = fmaf(dA, h, dlu.x * dlu.y * bc.x);
            float r = h * bc.y;
            r = dpp_add<0xB1>(r);
            r = dpp_add<0x4E>(r);
            r = dpp_add<0x141>(r);
            r = dpp_add<0x140>(r);
            if (s == 0) s_dlu[t * 32 + d * 2] = r + dlu.y * Dd;
        }
    }
    __syncthreads();

    // ---- Phase 5: y_gated = y * silu(z), z recomputed from staged x
    {
        const int d = tid & 15;
        float w[8];
        #pragma unroll
        for (int m = 0; m < 8; ++m) w[m] = in_proj_w[(16 + d) * 8 + m];
        for (int t = tid >> 4; t < SEQ; t += 16) {
            float z = 0.f;
            #pragma unroll
            for (int m = 0; m < 8; ++m) z += w[m] * s_x[m * SEQ + t];
            float sz = z / (1.f + __expf(-z));
            s_dlu[t * 32 + d * 2] *= sz;
        }
    }
    __syncthreads();

    // ---- Phase 5b: out2000[t*8+j] = sum_d y_gated[t,d] * out_proj_w[j,d] (into s_f)
    {
        const int j = tid & 7;
        float w[16];
        #pragma unroll
        for (int d2 = 0; d2 < 16; ++d2) w[d2] = out_proj_w[j * 16 + d2];
        for (int t = tid >> 3; t < SEQ; t += 32) {
            float a = 0.f;
            #pragma unroll
            for (int d2 = 0; d2 < 16; ++d2) a += w[d2] * s_dlu2[t * 16 + d2].x;
            s_f[t * 8 + j] = a;
        }
    }
    __syncthreads();

    // ---- Phase 6: logits[c] = flat(2000) . fc_w[c,:] + fc_b[c]
    {
        float p[NCLS];
        #pragma unroll
        for (int c = 0; c < NCLS; ++c) p[c] = 0.f;
        for (int idx = tid; idx < 2000; idx += 256) {
            float f = s_f[idx];
            #pragma unroll
            for (int c = 0; c < NCLS; ++c) p[c] += f * fc_w[c * 2000 + idx];
        }
        #pragma unroll
        for (int c = 0; c < NCLS; ++c) {
            float v = p[c];
            v += __shfl_xor(v, 1);
            v += __shfl_xor(v, 2);
            v += __shfl_xor(v, 4);
            v += __shfl_xor(v, 8);
            v += __shfl_xor(v, 16);
            v += __shfl_xor(v, 32);
            p[c] = v;
        }
        const int wave = tid >> 6;
        const int lane = tid & 63;
        if (lane == 0) {
            #pragma unroll
            for (int c = 0; c < NCLS; ++c) s_dt[wave * NCLS + c] = p[c];
        }
        __syncthreads();
        if (tid < NCLS) {
            float v = s_dt[tid] + s_dt[NCLS + tid] + s_dt[2 * NCLS + tid] +
                      s_dt[3 * NCLS + tid] + fc_b[tid];
            out[(size_t)b * NCLS + tid] = v;
        }
    }
}

extern "C" void kernel_launch(void* const* d_in, const int* in_sizes, int n_in,
                              void* d_out, int out_size, void* d_ws, size_t ws_size,
                              hipStream_t stream) {
    const float* x          = (const float*)d_in[0];
    const float* in_proj_w  = (const float*)d_in[1];
    const float* conv_w     = (const float*)d_in[2];
    const float* conv_b     = (const float*)d_in[3];
    const float* x_proj_w   = (const float*)d_in[4];
    const float* dt_proj_w  = (const float*)d_in[5];
    const float* dt_proj_b  = (const float*)d_in[6];
    const float* A_log      = (const float*)d_in[7];
    const float* Dp         = (const float*)d_in[8];
    const float* out_proj_w = (const float*)d_in[9];
    const float* fc_w       = (const float*)d_in[10];
    const float* fc_b       = (const float*)d_in[11];
    float* out = (float*)d_out;

    const int batch = in_sizes[0] / (8 * SEQ);  // 1024
    mamba_cls_kernel<<<batch, 256, 0, stream>>>(
        x, in_proj_w, conv_w, conv_b, x_proj_w, dt_proj_w, dt_proj_b,
        A_log, Dp, out_proj_w, fc_w, fc_b, out);
}

// Round 3
// 89.396 us; speedup vs baseline: 1.5365x; 1.1610x over previous
//
#include <hip/hip_runtime.h>
#include <hip/hip_fp16.h>
#include <math.h>

#define SEQ 250
#define NCLS 12

// Butterfly add via DPP within 16-lane rows (zero DS-pipe ops).
// 0xB1=quad_perm(1,0,3,2) xor1; 0x4E=quad_perm(2,3,0,1) xor2;
// 0x141=row_half_mirror (lane^7, valid once quad-constant);
// 0x140=row_mirror (lane^15, valid once 8-group-constant).
template<int CTRL>
__device__ __forceinline__ float dpp_add(float v) {
    int t = __builtin_amdgcn_update_dpp(0, __float_as_int(v), CTRL, 0xF, 0xF, true);
    return v + __int_as_float(t);
}

// One block per batch element, 256 threads.
// LDS: s_bc 17000 + s_dl 17000 + s_u 9000 + s_x 8000 + s_dt 1024 = 52,024 B
//  -> 3 blocks/CU (12 waves).
__global__ __launch_bounds__(256, 3)
void mamba_cls_kernel(
    const float* __restrict__ x,         // (B, 8, 250)
    const float* __restrict__ in_proj_w, // (32, 8)
    const float* __restrict__ conv_w,    // (16, 4)
    const float* __restrict__ conv_b,    // (16)
    const float* __restrict__ x_proj_w,  // (33, 16)
    const float* __restrict__ dt_proj_w, // (16, 1)
    const float* __restrict__ dt_proj_b, // (16)
    const float* __restrict__ A_log,     // (16, 16)
    const float* __restrict__ Dp,        // (16)
    const float* __restrict__ out_proj_w,// (8, 16)
    const float* __restrict__ fc_w,      // (12, 2000)
    const float* __restrict__ fc_b,      // (12)
    float* __restrict__ out)             // (B, 12)
{
    // s_bc: ph1-2 x_in (f32 view, [t*17+d]); ph3a+ {B,C} half2 [t*17+s];
    //       ph5b+ out2000 (f32 view, [t*8+j])
    __shared__ __align__(16) __half2 s_bc[SEQ * 17];
    __shared__ __align__(16) float   s_dl[SEQ * 17];  // dl -> y -> y_gated
    __shared__ __align__(16) __half  s_u [SEQ * 18];  // u, fp16, padded stride
    __shared__ __align__(16) float   s_x [SEQ * 8];   // staged x; later sz fp16 [t*16+d]
    __shared__ float s_dt[256];                        // dt(250); ph6 reduce buf

    const int b   = blockIdx.x;
    const int tid = threadIdx.x;
    float*  s_f  = (float*)s_bc;
    __half* s_sz = (__half*)s_x;

    // ---- Phase 0: stage x coalesced into LDS
    {
        const float* __restrict__ xb = x + (size_t)b * (8 * SEQ);
        for (int i = tid; i < 8 * SEQ; i += 256) s_x[i] = xb[i];
    }
    __syncthreads();

    // ---- Phase 1: x_in[t,d] (-> s_f) and silu(z)[t,d] (-> regs), sharing x loads
    float szr[16];
    {
        const int d = tid & 15;
        const int t0 = tid >> 4;
        float w1[8], w2[8];
        #pragma unroll
        for (int m = 0; m < 8; ++m) {
            w1[m] = in_proj_w[d * 8 + m];
            w2[m] = in_proj_w[(16 + d) * 8 + m];
        }
        #pragma unroll
        for (int i = 0; i < 16; ++i) {
            int t = t0 + i * 16;
            if (t < SEQ) {
                float acc = 0.f, z = 0.f;
                #pragma unroll
                for (int m = 0; m < 8; ++m) {
                    float xv = s_x[m * SEQ + t];
                    acc = fmaf(w1[m], xv, acc);
                    z   = fmaf(w2[m], xv, z);
                }
                s_f[t * 17 + d] = acc;
                szr[i] = z / (1.f + __expf(-z));
            }
        }
    }
    __syncthreads();

    // ---- Phase 2: causal conv(k=4)+SiLU -> u (fp16); store sz (fp16) over dead s_x
    {
        const int d = tid & 15;
        const int t0 = tid >> 4;
        float cw[4];
        #pragma unroll
        for (int k = 0; k < 4; ++k) cw[k] = conv_w[d * 4 + k];
        const float cb = conv_b[d];
        #pragma unroll
        for (int i = 0; i < 16; ++i) {
            int t = t0 + i * 16;
            if (t < SEQ) {
                float acc = cb;
                #pragma unroll
                for (int k = 0; k < 4; ++k) {
                    int tt = t + k - 3;
                    if (tt >= 0) acc = fmaf(cw[k], s_f[tt * 17 + d], acc);
                }
                float sg = 1.f / (1.f + __expf(-acc));
                s_u[t * 18 + d] = __float2half(acc * sg);
                s_sz[t * 16 + d] = __float2half(szr[i]);
            }
        }
    }
    __syncthreads();

    // ---- Phase 3a: {B,C} half2 pairs (overwrite x_in region) + dt(250)
    {
        const int s = tid & 15;
        float wb[16], wc[16];
        #pragma unroll
        for (int d2 = 0; d2 < 16; ++d2) wb[d2] = x_proj_w[(1 + s) * 16 + d2];
        #pragma unroll
        for (int d2 = 0; d2 < 16; ++d2) wc[d2] = x_proj_w[(17 + s) * 16 + d2];
        for (int t = tid >> 4; t < SEQ; t += 16) {
            const __half2* up = (const __half2*)(s_u + t * 18);
            float ab = 0.f, ac = 0.f;
            #pragma unroll
            for (int k = 0; k < 8; ++k) {
                float2 uv = __half22float2(up[k]);
                ab = fmaf(wb[2 * k], uv.x, fmaf(wb[2 * k + 1], uv.y, ab));
                ac = fmaf(wc[2 * k], uv.x, fmaf(wc[2 * k + 1], uv.y, ac));
            }
            s_bc[t * 17 + s] = __floats2half2_rn(ab, ac);
        }
        if (tid < SEQ) {
            const __half2* up = (const __half2*)(s_u + tid * 18);
            float a = 0.f;
            #pragma unroll
            for (int k = 0; k < 8; ++k) {
                float2 uv = __half22float2(up[k]);
                a = fmaf(x_proj_w[2 * k], uv.x, fmaf(x_proj_w[2 * k + 1], uv.y, a));
            }
            s_dt[tid] = a;
        }
    }
    __syncthreads();

    // ---- Phase 3b: dl[t,d] = softplus(dt[t]*dt_proj_w[d] + dt_proj_b[d])
    {
        const int d = tid & 15;
        const float dw = dt_proj_w[d];
        const float db = dt_proj_b[d];
        for (int t = tid >> 4; t < SEQ; t += 16) {
            float v = fmaf(s_dt[t], dw, db);
            float sp = (v > 20.f) ? v : __logf(1.f + __expf(v));
            s_dl[t * 17 + d] = sp;
        }
    }
    __syncthreads();

    // ---- Phase 4: scan. thread = (d = tid>>4, s = tid&15)
    {
        const int d = tid >> 4;
        const int s = tid & 15;
        const float A2 = -__expf(A_log[d * 16 + s]) * 1.4426950408889634f;
        const float Dd = Dp[d];
        float h = 0.f;
        #pragma unroll 5
        for (int t = 0; t < SEQ; ++t) {
            float dl = s_dl[t * 17 + d];                       // broadcast over s
            float uf = __half2float(s_u[t * 18 + d]);          // broadcast over s
            float2 bc = __half22float2(s_bc[t * 17 + s]);      // broadcast over d
            float dA = exp2f(dl * A2);
            h = fmaf(dA, h, dl * uf * bc.x);
            float r = h * bc.y;
            r = dpp_add<0xB1>(r);
            r = dpp_add<0x4E>(r);
            r = dpp_add<0x141>(r);
            r = dpp_add<0x140>(r);
            if (s == 0) s_dl[t * 17 + d] = fmaf(uf, Dd, r);    // y over dl slot
        }
    }
    __syncthreads();

    // ---- Phase 5: y *= silu(z) (sz fp16 from s_x region)
    {
        const int d = tid & 15;
        for (int t = tid >> 4; t < SEQ; t += 16) {
            float sz = __half2float(s_sz[t * 16 + d]);
            s_dl[t * 17 + d] *= sz;
        }
    }
    __syncthreads();

    // ---- Phase 5b: out2000[t*8+j] = sum_d y[t,d]*out_proj_w[j,d] (into s_f)
    {
        const int j = tid & 7;
        float w[16];
        #pragma unroll
        for (int d2 = 0; d2 < 16; ++d2) w[d2] = out_proj_w[j * 16 + d2];
        for (int t = tid >> 3; t < SEQ; t += 32) {
            float a = 0.f;
            #pragma unroll
            for (int d2 = 0; d2 < 16; ++d2) a = fmaf(w[d2], s_dl[t * 17 + d2], a);
            s_f[t * 8 + j] = a;
        }
    }
    __syncthreads();

    // ---- Phase 6: logits[c] = out2000 . fc_w[c,:] + fc_b[c]  (float2 + DPP reduce)
    {
        float p[NCLS];
        #pragma unroll
        for (int c = 0; c < NCLS; ++c) p[c] = 0.f;
        const float2* fw2 = (const float2*)fc_w;
        const float2* sf2 = (const float2*)s_f;
        for (int q = tid; q < 1000; q += 256) {
            float2 f = sf2[q];
            #pragma unroll
            for (int c = 0; c < NCLS; ++c) {
                float2 wv = fw2[c * 1000 + q];
                p[c] = fmaf(f.x, wv.x, fmaf(f.y, wv.y, p[c]));
            }
        }
        #pragma unroll
        for (int c = 0; c < NCLS; ++c) {
            float v = p[c];
            v = dpp_add<0xB1>(v);
            v = dpp_add<0x4E>(v);
            v = dpp_add<0x141>(v);
            v = dpp_add<0x140>(v);
            v += __shfl_xor(v, 16);
            v += __shfl_xor(v, 32);
            p[c] = v;
        }
        const int wave = tid >> 6;
        const int lane = tid & 63;
        if (lane == 0) {
            #pragma unroll
            for (int c = 0; c < NCLS; ++c) s_dt[wave * NCLS + c] = p[c];
        }
        __syncthreads();
        if (tid < NCLS) {
            float v = s_dt[tid] + s_dt[NCLS + tid] + s_dt[2 * NCLS + tid] +
                      s_dt[3 * NCLS + tid] + fc_b[tid];
            out[(size_t)b * NCLS + tid] = v;
        }
    }
}

extern "C" void kernel_launch(void* const* d_in, const int* in_sizes, int n_in,
                              void* d_out, int out_size, void* d_ws, size_t ws_size,
                              hipStream_t stream) {
    const float* x          = (const float*)d_in[0];
    const float* in_proj_w  = (const float*)d_in[1];
    const float* conv_w     = (const float*)d_in[2];
    const float* conv_b     = (const float*)d_in[3];
    const float* x_proj_w   = (const float*)d_in[4];
    const float* dt_proj_w  = (const float*)d_in[5];
    const float* dt_proj_b  = (const float*)d_in[6];
    const float* A_log      = (const float*)d_in[7];
    const float* Dp         = (const float*)d_in[8];
    const float* out_proj_w = (const float*)d_in[9];
    const float* fc_w       = (const float*)d_in[10];
    const float* fc_b       = (const float*)d_in[11];
    float* out = (float*)d_out;

    const int batch = in_sizes[0] / (8 * SEQ);  // 1024
    mamba_cls_kernel<<<batch, 256, 0, stream>>>(
        x, in_proj_w, conv_w, conv_b, x_proj_w, dt_proj_w, dt_proj_b,
        A_log, Dp, out_proj_w, fc_w, fc_b, out);
}

// Round 4
// 88.767 us; speedup vs baseline: 1.5474x; 1.0071x over previous
//
#include <hip/hip_runtime.h>
#include <hip/hip_fp16.h>
#include <math.h>

#define SEQ 250
#define NCLS 12

// Butterfly add via DPP within 16-lane rows (zero DS-pipe ops).
// 0xB1=quad_perm(1,0,3,2) xor1; 0x4E=quad_perm(2,3,0,1) xor2;
// 0x141=row_half_mirror (lane^7, valid once quad-constant);
// 0x140=row_mirror (lane^15, valid once 8-group-constant).
template<int CTRL>
__device__ __forceinline__ float dpp_add(float v) {
    int t = __builtin_amdgcn_update_dpp(0, __float_as_int(v), CTRL, 0xF, 0xF, true);
    return v + __int_as_float(t);
}

// One block per batch element, 256 threads.
// LDS: s_bc 16000 + s_dl 16000 + s_u 8000 = 40,000 B -> 4 blocks/CU (16 waves).
__global__ __launch_bounds__(256, 4)
void mamba_cls_kernel(
    const float* __restrict__ x,         // (B, 8, 250)
    const float* __restrict__ in_proj_w, // (32, 8)
    const float* __restrict__ conv_w,    // (16, 4)
    const float* __restrict__ conv_b,    // (16)
    const float* __restrict__ x_proj_w,  // (33, 16)
    const float* __restrict__ dt_proj_w, // (16, 1)
    const float* __restrict__ dt_proj_b, // (16)
    const float* __restrict__ A_log,     // (16, 16)
    const float* __restrict__ Dp,        // (16)
    const float* __restrict__ out_proj_w,// (8, 16)
    const float* __restrict__ fc_w,      // (12, 2000)
    const float* __restrict__ fc_b,      // (12)
    float* __restrict__ out)             // (B, 12)
{
    // s_bc: ph1 x_in (f32 view [t*16+d]); ph3+ {B,C} half2 [t*16+s];
    //       ph5b+ out2000 (f32 view [t*8+j])
    __shared__ __align__(16) __half2 s_bc[SEQ * 16];  // 16000 B
    __shared__ __align__(16) float   s_dl[SEQ * 16];  // dl -> y_raw -> y_gated; ph6 reduce buf
    __shared__ __align__(16) __half  s_u [SEQ * 16];  // u fp16

    const int b   = blockIdx.x;
    const int tid = threadIdx.x;
    float* s_f = (float*)s_bc;
    const float* __restrict__ xb = x + (size_t)b * (8 * SEQ);

    // ---- Phase 1: x_in[t,d] -> s_f ; silu(z)[t,d] -> registers (szr)
    float szr[16];
    {
        const int d  = tid & 15;
        const int t0 = tid >> 4;
        float w1[8], w2[8];
        #pragma unroll
        for (int m = 0; m < 8; ++m) {
            w1[m] = in_proj_w[d * 8 + m];
            w2[m] = in_proj_w[(16 + d) * 8 + m];
        }
        #pragma unroll
        for (int i = 0; i < 16; ++i) {
            int t = t0 + i * 16;
            if (t < SEQ) {
                float acc = 0.f, z = 0.f;
                #pragma unroll
                for (int m = 0; m < 8; ++m) {
                    float xv = xb[m * SEQ + t];   // L1-resident after first touch
                    acc = fmaf(w1[m], xv, acc);
                    z   = fmaf(w2[m], xv, z);
                }
                s_f[t * 16 + d] = acc;
                szr[i] = z / (1.f + __expf(-z));
            }
        }
    }
    __syncthreads();

    // ---- Phase 2: causal conv(k=4)+SiLU -> u (fp16)
    {
        const int d  = tid & 15;
        const int t0 = tid >> 4;
        float cw[4];
        #pragma unroll
        for (int k = 0; k < 4; ++k) cw[k] = conv_w[d * 4 + k];
        const float cb = conv_b[d];
        #pragma unroll
        for (int i = 0; i < 16; ++i) {
            int t = t0 + i * 16;
            if (t < SEQ) {
                float acc = cb;
                #pragma unroll
                for (int k = 0; k < 4; ++k) {
                    int tt = t + k - 3;
                    if (tt >= 0) acc = fmaf(cw[k], s_f[tt * 16 + d], acc);
                }
                float sg = 1.f / (1.f + __expf(-acc));
                s_u[t * 16 + d] = __float2half(acc * sg);
            }
        }
    }
    __syncthreads();

    // ---- Phase 3: {B,C} -> s_bc, dl -> s_dl (dt computed redundantly per s-lane)
    {
        const int s = tid & 15;
        __half2 wb2[8], wc2[8], wd2[8];
        #pragma unroll
        for (int k = 0; k < 8; ++k) {
            wb2[k] = __floats2half2_rn(x_proj_w[(1 + s) * 16 + 2 * k],
                                       x_proj_w[(1 + s) * 16 + 2 * k + 1]);
            wc2[k] = __floats2half2_rn(x_proj_w[(17 + s) * 16 + 2 * k],
                                       x_proj_w[(17 + s) * 16 + 2 * k + 1]);
            wd2[k] = __floats2half2_rn(x_proj_w[2 * k], x_proj_w[2 * k + 1]);
        }
        const float dws = dt_proj_w[s];
        const float dbs = dt_proj_b[s];
        const __half2 zero2 = __float2half2_rn(0.f);
        for (int t = tid >> 4; t < SEQ; t += 16) {
            const __half2* up = (const __half2*)(s_u + t * 16);
            __half2 ab = zero2, ac = zero2, ad = zero2;
            #pragma unroll
            for (int k = 0; k < 8; ++k) {
                __half2 uv = up[k];
                ab = __hfma2(uv, wb2[k], ab);
                ac = __hfma2(uv, wc2[k], ac);
                ad = __hfma2(uv, wd2[k], ad);
            }
            float abf = __half2float(__low2half(ab)) + __half2float(__high2half(ab));
            float acf = __half2float(__low2half(ac)) + __half2float(__high2half(ac));
            float adf = __half2float(__low2half(ad)) + __half2float(__high2half(ad));
            s_bc[t * 16 + s] = __floats2half2_rn(abf, acf);
            float v = fmaf(adf, dws, dbs);
            s_dl[t * 16 + s] = (v > 20.f) ? v : __logf(1.f + __expf(v));
        }
    }
    __syncthreads();

    // ---- Phase 4: scan. thread = (d = tid>>4, s = tid&15); whole wave shares t.
    {
        const int d = tid >> 4;
        const int s = tid & 15;
        const float A2 = -__expf(A_log[d * 16 + s]) * 1.4426950408889634f;
        const float Dd = Dp[d];
        float h = 0.f;
        #pragma unroll 5
        for (int t = 0; t < SEQ; ++t) {
            float dl = s_dl[t * 16 + d];                    // 4 addrs, distinct banks
            float uf = __half2float(s_u[t * 16 + d]);
            float2 bc = __half22float2(s_bc[t * 16 + s]);   // 16 addrs, distinct banks
            float dA = exp2f(dl * A2);
            h = fmaf(dA, h, dl * uf * bc.x);
            float r = h * bc.y;
            r = dpp_add<0xB1>(r);
            r = dpp_add<0x4E>(r);
            r = dpp_add<0x141>(r);
            r = dpp_add<0x140>(r);
            if (s == 0) s_dl[t * 16 + d] = fmaf(uf, Dd, r); // y_raw over dl slot
        }
    }
    __syncthreads();

    // ---- Phase 5: y *= silu(z) (registers, same mapping as phase 1)
    {
        const int d  = tid & 15;
        const int t0 = tid >> 4;
        #pragma unroll
        for (int i = 0; i < 16; ++i) {
            int t = t0 + i * 16;
            if (t < SEQ) s_dl[t * 16 + d] *= szr[i];
        }
    }
    __syncthreads();

    // ---- Phase 5b: out2000[t*8+j] = sum_d y[t,d]*out_proj_w[j,d] (into s_f)
    {
        const int j = tid & 7;
        float w[16];
        #pragma unroll
        for (int d2 = 0; d2 < 16; ++d2) w[d2] = out_proj_w[j * 16 + d2];
        for (int t = tid >> 3; t < SEQ; t += 32) {
            float a = 0.f;
            #pragma unroll
            for (int d2 = 0; d2 < 16; ++d2) a = fmaf(w[d2], s_dl[t * 16 + d2], a);
            s_f[t * 8 + j] = a;
        }
    }
    __syncthreads();

    // ---- Phase 6: logits[c] = out2000 . fc_w[c,:] + fc_b[c]  (float4 loads)
    {
        float p[NCLS];
        #pragma unroll
        for (int c = 0; c < NCLS; ++c) p[c] = 0.f;
        const float4* fw4 = (const float4*)fc_w;
        const float4* sf4 = (const float4*)s_f;
        for (int q = tid; q < 500; q += 256) {
            float4 f = sf4[q];
            #pragma unroll
            for (int c = 0; c < NCLS; ++c) {
                float4 wv = fw4[c * 500 + q];
                p[c] += f.x * wv.x + f.y * wv.y + f.z * wv.z + f.w * wv.w;
            }
        }
        #pragma unroll
        for (int c = 0; c < NCLS; ++c) {
            float v = p[c];
            v = dpp_add<0xB1>(v);
            v = dpp_add<0x4E>(v);
            v = dpp_add<0x141>(v);
            v = dpp_add<0x140>(v);
            v += __shfl_xor(v, 16);
            v += __shfl_xor(v, 32);
            p[c] = v;
        }
        const int wave = tid >> 6;
        const int lane = tid & 63;
        if (lane == 0) {
            #pragma unroll
            for (int c = 0; c < NCLS; ++c) s_dl[wave * NCLS + c] = p[c];
        }
        __syncthreads();
        if (tid < NCLS) {
            float v = s_dl[tid] + s_dl[NCLS + tid] + s_dl[2 * NCLS + tid] +
                      s_dl[3 * NCLS + tid] + fc_b[tid];
            out[(size_t)b * NCLS + tid] = v;
        }
    }
}

extern "C" void kernel_launch(void* const* d_in, const int* in_sizes, int n_in,
                              void* d_out, int out_size, void* d_ws, size_t ws_size,
                              hipStream_t stream) {
    const float* x          = (const float*)d_in[0];
    const float* in_proj_w  = (const float*)d_in[1];
    const float* conv_w     = (const float*)d_in[2];
    const float* conv_b     = (const float*)d_in[3];
    const float* x_proj_w   = (const float*)d_in[4];
    const float* dt_proj_w  = (const float*)d_in[5];
    const float* dt_proj_b  = (const float*)d_in[6];
    const float* A_log      = (const float*)d_in[7];
    const float* Dp         = (const float*)d_in[8];
    const float* out_proj_w = (const float*)d_in[9];
    const float* fc_w       = (const float*)d_in[10];
    const float* fc_b       = (const float*)d_in[11];
    float* out = (float*)d_out;

    const int batch = in_sizes[0] / (8 * SEQ);  // 1024
    mamba_cls_kernel<<<batch, 256, 0, stream>>>(
        x, in_proj_w, conv_w, conv_b, x_proj_w, dt_proj_w, dt_proj_b,
        A_log, Dp, out_proj_w, fc_w, fc_b, out);
}

// Round 5
// 74.997 us; speedup vs baseline: 1.8315x; 1.1836x over previous
//
#include <hip/hip_runtime.h>
#include <hip/hip_fp16.h>
#include <math.h>

#define SEQ 250
#define NCLS 12

// Butterfly add via DPP within 16-lane rows (zero DS-pipe ops).
// 0xB1=quad_perm(1,0,3,2) xor1; 0x4E=quad_perm(2,3,0,1) xor2;
// 0x141=row_half_mirror (lane^7, valid once quad-constant);
// 0x140=row_mirror (lane^15, valid once 8-group-constant).
template<int CTRL>
__device__ __forceinline__ float dpp_add(float v) {
    int t = __builtin_amdgcn_update_dpp(0, __float_as_int(v), CTRL, 0xF, 0xF, true);
    return v + __int_as_float(t);
}

// One block per batch element, 256 threads.
// LDS: s_bc 16000 + s_dlu 16000 + s_u 8000 = 40,000 B -> 4 blocks/CU (16 waves).
__global__ __launch_bounds__(256, 4)
void mamba_cls_kernel(
    const float* __restrict__ x,         // (B, 8, 250)
    const float* __restrict__ in_proj_w, // (32, 8)
    const float* __restrict__ conv_w,    // (16, 4)
    const float* __restrict__ conv_b,    // (16)
    const float* __restrict__ x_proj_w,  // (33, 16)
    const float* __restrict__ dt_proj_w, // (16, 1)
    const float* __restrict__ dt_proj_b, // (16)
    const float* __restrict__ A_log,     // (16, 16)
    const float* __restrict__ Dp,        // (16)
    const float* __restrict__ out_proj_w,// (8, 16)
    const float* __restrict__ fc_w,      // (12, 2000)
    const float* __restrict__ fc_b,      // (12)
    float* __restrict__ out)             // (B, 12)
{
    // s_bc : ph1 x_in (f32 view [t*16+d]); ph3+ {B,C} half2 [t*16+s];
    //        ph5b+ out2000 (f32 view [t*8+j])
    // s_dlu: ph3+ {dl,dl*u} half2 [t*16+s]; ph4+ y (f32 view, same word); ph6 partials
    // s_u  : ph0-1 staged x (f32 view, 2000 floats); ph2+ u fp16 [t*16+d]
    __shared__ __align__(16) __half2 s_bc [SEQ * 16];
    __shared__ __align__(16) __half2 s_dlu[SEQ * 16];
    __shared__ __align__(16) __half  s_u  [SEQ * 16];

    const int b   = blockIdx.x;
    const int tid = threadIdx.x;
    float* s_f  = (float*)s_bc;
    float* s_y  = (float*)s_dlu;
    float* s_xf = (float*)s_u;

    // ---- Phase 0: stage x coalesced into the (future) u region
    {
        const float* __restrict__ xb = x + (size_t)b * (8 * SEQ);
        for (int i = tid; i < 8 * SEQ; i += 256) s_xf[i] = xb[i];
    }
    __syncthreads();

    // ---- Phase 1: x_in[t,d] -> s_f ; silu(z)[t,d] -> registers (szr)
    float szr[16];
    {
        const int d  = tid & 15;
        const int t0 = tid >> 4;
        float w1[8], w2[8];
        #pragma unroll
        for (int m = 0; m < 8; ++m) {
            w1[m] = in_proj_w[d * 8 + m];
            w2[m] = in_proj_w[(16 + d) * 8 + m];
        }
        #pragma unroll
        for (int i = 0; i < 16; ++i) {
            int t = t0 + i * 16;
            if (t < SEQ) {
                float acc = 0.f, z = 0.f;
                #pragma unroll
                for (int m = 0; m < 8; ++m) {
                    float xv = s_xf[m * SEQ + t];
                    acc = fmaf(w1[m], xv, acc);
                    z   = fmaf(w2[m], xv, z);
                }
                s_f[t * 16 + d] = acc;
                szr[i] = z / (1.f + __expf(-z));
            }
        }
    }
    __syncthreads();

    // ---- Phase 2: causal conv(k=4)+SiLU -> u fp16 (overwrites dead x staging)
    {
        const int d  = tid & 15;
        const int t0 = tid >> 4;
        float cw[4];
        #pragma unroll
        for (int k = 0; k < 4; ++k) cw[k] = conv_w[d * 4 + k];
        const float cb = conv_b[d];
        #pragma unroll
        for (int i = 0; i < 16; ++i) {
            int t = t0 + i * 16;
            if (t < SEQ) {
                float acc = cb;
                #pragma unroll
                for (int k = 0; k < 4; ++k) {
                    int tt = t + k - 3;
                    if (tt >= 0) acc = fmaf(cw[k], s_f[tt * 16 + d], acc);
                }
                float sg = 1.f / (1.f + __expf(-acc));
                s_u[t * 16 + d] = __float2half(acc * sg);
            }
        }
    }
    __syncthreads();

    // ---- Phase 3: {B,C} -> s_bc ; {dl, dl*u} -> s_dlu (dt redundant per s-lane)
    {
        const int s = tid & 15;
        __half2 wb2[8], wc2[8], wd2[8];
        #pragma unroll
        for (int k = 0; k < 8; ++k) {
            wb2[k] = __floats2half2_rn(x_proj_w[(1 + s) * 16 + 2 * k],
                                       x_proj_w[(1 + s) * 16 + 2 * k + 1]);
            wc2[k] = __floats2half2_rn(x_proj_w[(17 + s) * 16 + 2 * k],
                                       x_proj_w[(17 + s) * 16 + 2 * k + 1]);
            wd2[k] = __floats2half2_rn(x_proj_w[2 * k], x_proj_w[2 * k + 1]);
        }
        const float dws = dt_proj_w[s];
        const float dbs = dt_proj_b[s];
        const __half2 zero2 = __float2half2_rn(0.f);
        for (int t = tid >> 4; t < SEQ; t += 16) {
            const __half2* up = (const __half2*)(s_u + t * 16);
            __half2 ab = zero2, ac = zero2, ad = zero2;
            #pragma unroll
            for (int k = 0; k < 8; ++k) {
                __half2 uv = up[k];
                ab = __hfma2(uv, wb2[k], ab);
                ac = __hfma2(uv, wc2[k], ac);
                ad = __hfma2(uv, wd2[k], ad);
            }
            float abf = __half2float(__low2half(ab)) + __half2float(__high2half(ab));
            float acf = __half2float(__low2half(ac)) + __half2float(__high2half(ac));
            float adf = __half2float(__low2half(ad)) + __half2float(__high2half(ad));
            s_bc[t * 16 + s] = __floats2half2_rn(abf, acf);
            float v  = fmaf(adf, dws, dbs);
            float dl = (v > 20.f) ? v : __logf(1.f + __expf(v));
            float uf = __half2float(s_u[t * 16 + s]);
            s_dlu[t * 16 + s] = __floats2half2_rn(dl, dl * uf);
        }
    }
    __syncthreads();

    // ---- Phase 4: scan. thread = (d = tid>>4, s = tid&15); 2 LDS reads per t.
    {
        const int d = tid >> 4;
        const int s = tid & 15;
        const float A2 = -__expf(A_log[d * 16 + s]) * 1.4426950408889634f;
        float h = 0.f;
        #pragma unroll 5
        for (int t = 0; t < SEQ; ++t) {
            float2 dlu = __half22float2(s_dlu[t * 16 + d]);  // {dl, dl*u} bcast over s
            float2 bc  = __half22float2(s_bc [t * 16 + s]);  // {B, C}    bcast over d
            float dA = exp2f(dlu.x * A2);
            h = fmaf(dA, h, dlu.y * bc.x);
            float r = h * bc.y;
            r = dpp_add<0xB1>(r);
            r = dpp_add<0x4E>(r);
            r = dpp_add<0x141>(r);
            r = dpp_add<0x140>(r);
            if (s == 0) s_y[t * 16 + d] = r;   // y_raw over the dead {dl,dlu} word
        }
    }
    __syncthreads();

    // ---- Phase 5: y = (y_raw + u*D) * silu(z)
    {
        const int d  = tid & 15;
        const int t0 = tid >> 4;
        const float Dd = Dp[d];
        #pragma unroll
        for (int i = 0; i < 16; ++i) {
            int t = t0 + i * 16;
            if (t < SEQ) {
                float uf = __half2float(s_u[t * 16 + d]);
                s_y[t * 16 + d] = fmaf(uf, Dd, s_y[t * 16 + d]) * szr[i];
            }
        }
    }
    __syncthreads();

    // ---- Phase 5b: out2000[t*8+j] = sum_d y[t,d]*out_proj_w[j,d] (into s_f)
    {
        const int j = tid & 7;
        float w[16];
        #pragma unroll
        for (int d2 = 0; d2 < 16; ++d2) w[d2] = out_proj_w[j * 16 + d2];
        for (int t = tid >> 3; t < SEQ; t += 32) {
            float a = 0.f;
            #pragma unroll
            for (int d2 = 0; d2 < 16; ++d2) a = fmaf(w[d2], s_y[t * 16 + d2], a);
            s_f[t * 8 + j] = a;
        }
    }
    __syncthreads();

    // ---- Phase 6: logits[c] = out2000 . fc_w[c,:] + fc_b[c]  (float4 loads)
    {
        float p[NCLS];
        #pragma unroll
        for (int c = 0; c < NCLS; ++c) p[c] = 0.f;
        const float4* fw4 = (const float4*)fc_w;
        const float4* sf4 = (const float4*)s_f;
        for (int q = tid; q < 500; q += 256) {
            float4 f = sf4[q];
            #pragma unroll
            for (int c = 0; c < NCLS; ++c) {
                float4 wv = fw4[c * 500 + q];
                p[c] += f.x * wv.x + f.y * wv.y + f.z * wv.z + f.w * wv.w;
            }
        }
        #pragma unroll
        for (int c = 0; c < NCLS; ++c) {
            float v = p[c];
            v = dpp_add<0xB1>(v);
            v = dpp_add<0x4E>(v);
            v = dpp_add<0x141>(v);
            v = dpp_add<0x140>(v);
            v += __shfl_xor(v, 16);
            v += __shfl_xor(v, 32);
            p[c] = v;
        }
        const int wave = tid >> 6;
        const int lane = tid & 63;
        if (lane == 0) {
            #pragma unroll
            for (int c = 0; c < NCLS; ++c) s_y[wave * NCLS + c] = p[c];
        }
        __syncthreads();
        if (tid < NCLS) {
            float v = s_y[tid] + s_y[NCLS + tid] + s_y[2 * NCLS + tid] +
                      s_y[3 * NCLS + tid] + fc_b[tid];
            out[(size_t)b * NCLS + tid] = v;
        }
    }
}

extern "C" void kernel_launch(void* const* d_in, const int* in_sizes, int n_in,
                              void* d_out, int out_size, void* d_ws, size_t ws_size,
                              hipStream_t stream) {
    const float* x          = (const float*)d_in[0];
    const float* in_proj_w  = (const float*)d_in[1];
    const float* conv_w     = (const float*)d_in[2];
    const float* conv_b     = (const float*)d_in[3];
    const float* x_proj_w   = (const float*)d_in[4];
    const float* dt_proj_w  = (const float*)d_in[5];
    const float* dt_proj_b  = (const float*)d_in[6];
    const float* A_log      = (const float*)d_in[7];
    const float* Dp         = (const float*)d_in[8];
    const float* out_proj_w = (const float*)d_in[9];
    const float* fc_w       = (const float*)d_in[10];
    const float* fc_b       = (const float*)d_in[11];
    float* out = (float*)d_out;

    const int batch = in_sizes[0] / (8 * SEQ);  // 1024
    mamba_cls_kernel<<<batch, 256, 0, stream>>>(
        x, in_proj_w, conv_w, conv_b, x_proj_w, dt_proj_w, dt_proj_b,
        A_log, Dp, out_proj_w, fc_w, fc_b, out);
}